// Round 3
// baseline (97.436 us; speedup 1.0000x reference)
//
#include <hip/hip_runtime.h>

// LocalConvolutionMixMerge: per-pixel local conv, 3x3 + 5x5, weights shared
// across 8 channel groups (c % 32).
//
// R3: split the 3x3 and 5x5 convolutions into separate thread populations
// (k dimension in the grid). Doubles resident waves (4 -> 8 per SIMD) for
// latency hiding; weight loads split 9/25 with no duplication; x re-reads
// between the two populations are served by L2/L3.
//
// Wave = one full image row (w=0..63): horizontal taps via DPP wave shifts
// (zero-fill at wave edge == image zero padding in w).

#define HW_ 4096

__device__ __forceinline__ float dpp_shl1(float v) {  // D[i] = S[i+1]; lane63 -> 0
  return __builtin_bit_cast(
      float, __builtin_amdgcn_update_dpp(0, __builtin_bit_cast(int, v),
                                         0x130, 0xF, 0xF, true));
}
__device__ __forceinline__ float dpp_shr1(float v) {  // D[i] = S[i-1]; lane0 -> 0
  return __builtin_bit_cast(
      float, __builtin_amdgcn_update_dpp(0, __builtin_bit_cast(int, v),
                                         0x138, 0xF, 0xF, true));
}

__global__ __launch_bounds__(256) void lconv_mix_kernel(
    const float* __restrict__ x, const float* __restrict__ wgt,
    float* __restrict__ out) {
  int idx = blockIdx.x * blockDim.x + threadIdx.x;  // [N][K=2][WC=32][H][W]
  int w  = idx & 63;
  int h  = (idx >> 6) & 63;
  int wc = (idx >> 12) & 31;
  int k  = (idx >> 17) & 1;
  int n  = idx >> 18;

  const float* wbase = wgt + (size_t)n * 1088 * HW_ + h * 64 + w;
  const float* xn = x + (size_t)n * 256 * HW_ + h * 64 + w;
  float* o = out + ((size_t)((n * 2 + k) * 256)) * HW_ + h * 64 + w;

  if (k == 0) {  // 3x3, pad 1 — block-uniform branch
    float w1[9];
#pragma unroll
    for (int t = 0; t < 9; ++t)
      w1[t] = __builtin_nontemporal_load(&wbase[(size_t)(wc * 9 + t) * HW_]);

#pragma unroll
    for (int g = 0; g < 8; ++g) {
      int cc = g * 32 + wc;
      const float* xc = xn + (size_t)cc * HW_;
      float a = 0.0f;
#pragma unroll
      for (int i = 0; i < 3; ++i) {
        int hh = h + i - 1;
        float r = ((unsigned)hh < 64u) ? xc[(i - 1) * 64] : 0.0f;
        float m1 = dpp_shr1(r);
        float q1 = dpp_shl1(r);
        a = fmaf(m1, w1[i * 3 + 0], a);
        a = fmaf(r,  w1[i * 3 + 1], a);
        a = fmaf(q1, w1[i * 3 + 2], a);
      }
      __builtin_nontemporal_store(a, &o[(size_t)cc * HW_]);
    }
  } else {  // 5x5, pad 2
    float w2[25];
#pragma unroll
    for (int t = 0; t < 25; ++t)
      w2[t] = __builtin_nontemporal_load(&wbase[(size_t)(288 + wc * 25 + t) * HW_]);

#pragma unroll
    for (int g = 0; g < 8; ++g) {
      int cc = g * 32 + wc;
      const float* xc = xn + (size_t)cc * HW_;
      float a = 0.0f;
#pragma unroll
      for (int i = 0; i < 5; ++i) {
        int hh = h + i - 2;
        float r = ((unsigned)hh < 64u) ? xc[(i - 2) * 64] : 0.0f;
        float m1 = dpp_shr1(r);
        float m2 = dpp_shr1(m1);
        float q1 = dpp_shl1(r);
        float q2 = dpp_shl1(q1);
        a = fmaf(m2, w2[i * 5 + 0], a);
        a = fmaf(m1, w2[i * 5 + 1], a);
        a = fmaf(r,  w2[i * 5 + 2], a);
        a = fmaf(q1, w2[i * 5 + 3], a);
        a = fmaf(q2, w2[i * 5 + 4], a);
      }
      __builtin_nontemporal_store(a, &o[(size_t)cc * HW_]);
    }
  }
}

extern "C" void kernel_launch(void* const* d_in, const int* in_sizes, int n_in,
                              void* d_out, int out_size, void* d_ws,
                              size_t ws_size, hipStream_t stream) {
  const float* x = (const float*)d_in[0];
  const float* wgt = (const float*)d_in[1];
  float* out = (float*)d_out;

  int total = 2 * 2 * 32 * 64 * 64;  // N * K * WC * H * W
  lconv_mix_kernel<<<dim3(total / 256), dim3(256), 0, stream>>>(x, wgt, out);
}